// Round 20
// baseline (1991.026 us; speedup 1.0000x reference)
//
#include <hip/hip_runtime.h>
#include <hip/hip_bf16.h>
#include <stdint.h>

typedef __bf16 bf16_t;
typedef __attribute__((ext_vector_type(8))) __bf16 bf16x8;
typedef __attribute__((ext_vector_type(4))) __bf16 bf16x4;
typedef __attribute__((ext_vector_type(4))) float f32x4;
typedef __attribute__((ext_vector_type(8))) unsigned short u16x8;

#define M_TOK 2304
#define DV    1024
#define DLAT  4096
#define VOCAB 32000

__device__ __forceinline__ float bf2f(unsigned short u) {
  union { unsigned int i; float f; } v; v.i = ((unsigned int)u) << 16; return v.f;
}
__device__ __forceinline__ bf16_t f2bf(float f) { return (bf16_t)f; }

// async global->LDS, 16B per lane; LDS dest = wave-uniform base + lane*16
#define GLOAD16(gp, lp) \
  __builtin_amdgcn_global_load_lds( \
      (const __attribute__((address_space(1))) unsigned int*)(const void*)(gp), \
      (__attribute__((address_space(3))) unsigned int*)(void*)(lp), 16, 0, 0)

// ==== 256x128 bf16 NT GEMM, 256 thr, 3-buf vmcnt(6) (R9 schedule scaled) ====
// Rationale: staging-throughput-bound at 128^2 (9.2 GB staged); 256x128 tiles
// stage 25% less (6.9 GB) at 72 KB LDS -> still 2 independent blocks/CU.
// 4 waves, wave-tile 64(M) x 128(N): NFM=4, NFN=8, 32 MFMA/wave/tile.
// Swizzle identical to PMC-verified-0: col pre-permute + XOR read slot.
// EPI: 1 = bf16 store, 2 = f32 split store (sp -> Cp/Cp2/Cp3/Cp4).
template<int EPI>
__global__ void __launch_bounds__(256, 2)
gemm256r(const bf16_t* __restrict__ Ap, const bf16_t* __restrict__ Bp,
         void* __restrict__ Cp, void* __restrict__ Cp2,
         void* __restrict__ Cp3, void* __restrict__ Cp4,
         int Ksplit, int ld, int ldc, int Mt, int Nt)
{
  __shared__ __align__(16) bf16_t Al[3][256 * 32];   // 3 x 16 KB
  __shared__ __align__(16) bf16_t Bl[3][128 * 32];   // 3 x 8 KB

  // bijective XCD-chunked swizzle (m204)
  const int nwg = gridDim.x;
  const int orig = blockIdx.x;
  const int q = nwg >> 3, r = nwg & 7;
  const int xcd = orig & 7, idx = orig >> 3;
  const int wg = (xcd < r ? xcd * (q + 1) : r * (q + 1) + (xcd - r) * q) + idx;
  const int mt = wg % Mt;
  const int nt = (wg / Mt) % Nt;        // consecutive wg share B panel
  const int sp = wg / (Mt * Nt);        // split-K index
  const int m0 = mt * 256, n0 = nt * 128;
  const int kbase = sp * Ksplit;

  const int t    = threadIdx.x;
  const int lane = t & 63, wv = t >> 6;   // 4 waves, stacked in M
  const int lr = lane & 15, kc = lane >> 4;

  f32x4 acc[4][8];
#pragma unroll
  for (int i = 0; i < 4; ++i)
#pragma unroll
    for (int j = 0; j < 8; ++j)
#pragma unroll
      for (int x = 0; x < 4; ++x) acc[i][j][x] = 0.0f;

  const int rql = lane >> 2;
  const int cbs = (((lane & 3) ^ ((lane >> 3) & 3)) * 16);  // swizzled col byte
  const int sw8 = (kc ^ ((lr >> 1) & 3)) * 8;               // read-side XOR slot
  const size_t rstride = (size_t)ld * 2;

  const int NT = Ksplit / 32;

  auto STAGE = [&](int kt, int nb) {
    const size_t kb = (size_t)(kbase + kt * 32) * 2;
    // A: 4 waves x 64 rows = 256 (4 gloads/wave)
    const char* ga = (const char*)Ap + (size_t)(m0 + wv * 64 + rql) * rstride + kb + cbs;
    char* la = (char*)&Al[nb][0] + wv * 4096;
    GLOAD16(ga, la);
    GLOAD16(ga + 16 * rstride, la + 1024);
    GLOAD16(ga + 32 * rstride, la + 2048);
    GLOAD16(ga + 48 * rstride, la + 3072);
    // B: 4 waves x 32 rows = 128 (2 gloads/wave)
    const char* gb = (const char*)Bp + (size_t)(n0 + wv * 32 + rql) * rstride + kb + cbs;
    char* lb = (char*)&Bl[nb][0] + wv * 2048;
    GLOAD16(gb, lb);
    GLOAD16(gb + 16 * rstride, lb + 1024);
  };

  auto COMPUTE = [&](int nb) {
    bf16x8 af[4], bfv[8];
#pragma unroll
    for (int f = 0; f < 4; ++f)
      af[f] = *(const bf16x8*)(&Al[nb][(wv * 64 + f * 16 + lr) * 32 + sw8]);
#pragma unroll
    for (int f = 0; f < 8; ++f)
      bfv[f] = *(const bf16x8*)(&Bl[nb][(f * 16 + lr) * 32 + sw8]);
    __builtin_amdgcn_s_setprio(1);
#pragma unroll
    for (int i = 0; i < 4; ++i)
#pragma unroll
      for (int j = 0; j < 8; ++j)
        acc[i][j] = __builtin_amdgcn_mfma_f32_16x16x32_bf16(af[i], bfv[j], acc[i][j], 0, 0, 0);
    __builtin_amdgcn_s_setprio(0);
  };

  auto BARX = [&]() {
    asm volatile("s_waitcnt lgkmcnt(0)" ::: "memory");
    __builtin_amdgcn_s_barrier();
  };

  // prologue: stage tiles 0,1; wait tile 0 only (tile 1's 6 loads in flight)
  STAGE(0, 0);
  STAGE(1, 1);
  asm volatile("s_waitcnt vmcnt(6)" ::: "memory");
  __builtin_amdgcn_s_barrier();

  int bc = 0, bn = 1, bs = 2;
  for (int kt = 0; kt < NT - 2; ++kt) {
    STAGE(kt + 2, bs);                  // 6 loads fly under COMPUTE + barrier
    COMPUTE(bc);
    asm volatile("s_waitcnt vmcnt(6)" ::: "memory");  // tile kt+1 landed
    BARX();
    const int tmp = bc; bc = bn; bn = bs; bs = tmp;
  }
  COMPUTE(bc);
  asm volatile("s_waitcnt vmcnt(0)" ::: "memory");
  BARX();
  COMPUTE(bn);

  // epilogue
  float* Cf = nullptr;
  if (EPI == 2)
    Cf = (sp == 0) ? (float*)Cp : (sp == 1) ? (float*)Cp2
       : (sp == 2) ? (float*)Cp3 : (float*)Cp4;
#pragma unroll
  for (int j = 0; j < 8; ++j) {
    const int col = n0 + j * 16 + lr;
#pragma unroll
    for (int i = 0; i < 4; ++i) {
      const int row = m0 + wv * 64 + i * 16 + kc * 4;
      f32x4 a4 = acc[i][j];
      if (EPI == 1) {
        bf16_t* C = (bf16_t*)Cp;
#pragma unroll
        for (int x = 0; x < 4; ++x) C[(size_t)(row + x) * ldc + col] = f2bf(a4[x]);
      } else {
#pragma unroll
        for (int x = 0; x < 4; ++x) Cf[(size_t)(row + x) * ldc + col] = a4[x];
      }
    }
  }
}

// ========= 128x128 bf16 NT GEMM (R9-proven; GEMM1 only) =====================
constexpr int GBM = 128, GBN = 128, GBK = 32;

__global__ void __launch_bounds__(256, 3)
gemm_bb1(const bf16_t* __restrict__ Ap, const bf16_t* __restrict__ Bp,
         float* __restrict__ Cp, const float* __restrict__ bias,
         int K, int ld, int ldc, int Mt)
{
  __shared__ __align__(16) bf16_t Al[3][GBM * GBK];
  __shared__ __align__(16) bf16_t Bl[3][GBN * GBK];

  const int nwg = gridDim.x;
  const int orig = blockIdx.x;
  const int q = nwg >> 3, r = nwg & 7;
  const int xcd = orig & 7, idx = orig >> 3;
  const int wg = (xcd < r ? xcd * (q + 1) : r * (q + 1) + (xcd - r) * q) + idx;
  const int mt = wg % Mt, nt = wg / Mt;
  const int m0 = mt * GBM, n0 = nt * GBN;

  const int t    = threadIdx.x;
  const int lane = t & 63, wv = t >> 6;
  const int wm = wv >> 1, wn = wv & 1;
  const int lr = lane & 15, kc = lane >> 4;

  f32x4 acc[4][4];
#pragma unroll
  for (int i = 0; i < 4; ++i)
#pragma unroll
    for (int j = 0; j < 4; ++j)
#pragma unroll
      for (int x = 0; x < 4; ++x) acc[i][j][x] = 0.0f;

  const int rql = lane >> 2;
  const int cbs = (((lane & 3) ^ ((lane >> 3) & 3)) * 16);
  const int sw8 = (kc ^ ((lr >> 1) & 3)) * 8;
  const size_t rstride = (size_t)ld * 2;

  const int NT = K / GBK;

  auto STAGE = [&](int kt, int nb) {
    const size_t kb = (size_t)kt * GBK * 2;
    const char* ga = (const char*)Ap + (size_t)(m0 + wv * 32 + rql) * rstride + kb + cbs;
    char* la = (char*)&Al[nb][0] + wv * 2048;
    GLOAD16(ga, la);
    GLOAD16(ga + 16 * rstride, la + 1024);
    const char* gb = (const char*)Bp + (size_t)(n0 + wv * 32 + rql) * rstride + kb + cbs;
    char* lb = (char*)&Bl[nb][0] + wv * 2048;
    GLOAD16(gb, lb);
    GLOAD16(gb + 16 * rstride, lb + 1024);
  };

  auto COMPUTE = [&](int nb) {
    bf16x8 af[4], bfv[4];
#pragma unroll
    for (int f = 0; f < 4; ++f)
      af[f] = *(const bf16x8*)(&Al[nb][(wm * 64 + f * 16 + lr) * GBK + sw8]);
#pragma unroll
    for (int f = 0; f < 4; ++f)
      bfv[f] = *(const bf16x8*)(&Bl[nb][(wn * 64 + f * 16 + lr) * GBK + sw8]);
    __builtin_amdgcn_s_setprio(1);
#pragma unroll
    for (int i = 0; i < 4; ++i)
#pragma unroll
      for (int j = 0; j < 4; ++j)
        acc[i][j] = __builtin_amdgcn_mfma_f32_16x16x32_bf16(af[i], bfv[j], acc[i][j], 0, 0, 0);
    __builtin_amdgcn_s_setprio(0);
  };

  auto BARX = [&]() {
    asm volatile("s_waitcnt lgkmcnt(0)" ::: "memory");
    __builtin_amdgcn_s_barrier();
  };

  STAGE(0, 0);
  STAGE(1, 1);
  asm volatile("s_waitcnt vmcnt(4)" ::: "memory");
  __builtin_amdgcn_s_barrier();

  int bc = 0, bn = 1, bs = 2;
  for (int kt = 0; kt < NT - 2; ++kt) {
    STAGE(kt + 2, bs);
    COMPUTE(bc);
    asm volatile("s_waitcnt vmcnt(4)" ::: "memory");
    BARX();
    const int tmp = bc; bc = bn; bn = bs; bs = tmp;
  }
  COMPUTE(bc);
  asm volatile("s_waitcnt vmcnt(0)" ::: "memory");
  BARX();
  COMPUTE(bn);

#pragma unroll
  for (int j = 0; j < 4; ++j) {
    const int col = n0 + wn * 64 + j * 16 + lr;
    const float bv = bias[col];
#pragma unroll
    for (int i = 0; i < 4; ++i) {
      const int row = m0 + wm * 64 + i * 16 + kc * 4;
      f32x4 a4 = acc[i][j];
#pragma unroll
      for (int x = 0; x < 4; ++x) Cp[(size_t)(row + x) * ldc + col] = a4[x] + bv;
    }
  }
}

// -------- out += partials (split-K reduction), f32 --------
__global__ void __launch_bounds__(256)
addk3(float* __restrict__ out, const float* __restrict__ pa,
      const float* __restrict__ pb, const float* __restrict__ pc, int n4)
{
  const int stride = gridDim.x * 256;
  for (int i = blockIdx.x * 256 + threadIdx.x; i < n4; i += stride) {
    f32x4 a = *(const f32x4*)(out + i * 4);
    f32x4 b = *(const f32x4*)(pa + i * 4);
    f32x4 c = *(const f32x4*)(pb + i * 4);
    f32x4 d = *(const f32x4*)(pc + i * 4);
#pragma unroll
    for (int x = 0; x < 4; ++x) a[x] += b[x] + c[x] + d[x];
    *(f32x4*)(out + i * 4) = a;
  }
}

__global__ void __launch_bounds__(256)
addk(float* __restrict__ out, const float* __restrict__ part, int n4)
{
  const int stride = gridDim.x * 256;
  for (int i = blockIdx.x * 256 + threadIdx.x; i < n4; i += stride) {
    f32x4 a = *(const f32x4*)(out + i * 4);
    f32x4 b = *(const f32x4*)(part + i * 4);
#pragma unroll
    for (int x = 0; x < 4; ++x) a[x] += b[x];
    *(f32x4*)(out + i * 4) = a;
  }
}

// -------- stream convert f32 -> bf16 (same layout) --------
__global__ void __launch_bounds__(256)
cvt_bf16_k(const float* __restrict__ in, bf16_t* __restrict__ out, long n8)
{
  const long stride = (long)gridDim.x * 256;
  for (long i = (long)blockIdx.x * 256 + threadIdx.x; i < n8; i += stride) {
    f32x4 a = *(const f32x4*)(in + i * 8);
    f32x4 b = *(const f32x4*)(in + i * 8 + 4);
    bf16x8 o;
#pragma unroll
    for (int j = 0; j < 4; ++j) { o[j] = f2bf(a[j]); o[j + 4] = f2bf(b[j]); }
    *(bf16x8*)(out + i * 8) = o;
  }
}

// -------- Emb [32000][4096] f32 -> EmbT [4096][32000] bf16 (LDS-tiled) ------
__global__ void __launch_bounds__(256)
embT_k(const float* __restrict__ E, bf16_t* __restrict__ ET)
{
  __shared__ bf16_t tl[64][72];
  const int vb = blockIdx.x % (VOCAB / 64);
  const int eb = blockIdx.x / (VOCAB / 64);
  const int v0 = vb * 64, e0 = eb * 64;
  const int t = threadIdx.x;

  const int rr = t >> 4, c4 = (t & 15) * 4;
#pragma unroll
  for (int p = 0; p < 4; ++p) {
    const float* src = E + (size_t)(v0 + rr + p * 16) * DLAT + e0 + c4;
    f32x4 a = *(const f32x4*)src;
#pragma unroll
    for (int j = 0; j < 4; ++j) tl[c4 + j][rr + p * 16] = f2bf(a[j]);
  }
  __syncthreads();

  const int el = t >> 3, v8 = (t & 7) * 8;
#pragma unroll
  for (int p = 0; p < 2; ++p) {
    bf16x8 o = *(const bf16x8*)(&tl[el + p * 32][v8]);
    *(bf16x8*)(ET + (size_t)(e0 + el + p * 32) * VOCAB + v0 + v8) = o;
  }
}

// -------- LayerNorm over last dim (4096), f32 in -> bf16 out --------
__global__ void __launch_bounds__(256)
ln_k(const float* __restrict__ x, bf16_t* __restrict__ xn)
{
  __shared__ float sm[4];
  const int row = blockIdx.x, t = threadIdx.x;
  const float* xr = x + (size_t)row * DLAT;
  f32x4 v[4];
#pragma unroll
  for (int i = 0; i < 4; ++i) v[i] = *(const f32x4*)(xr + (t + i * 256) * 4);

  float s = 0.0f;
#pragma unroll
  for (int i = 0; i < 4; ++i)
#pragma unroll
    for (int j = 0; j < 4; ++j) s += v[i][j];
#pragma unroll
  for (int o = 32; o > 0; o >>= 1) s += __shfl_xor(s, o, 64);
  if ((t & 63) == 0) sm[t >> 6] = s;
  __syncthreads();
  const float mean = (sm[0] + sm[1] + sm[2] + sm[3]) * (1.0f / DLAT);
  __syncthreads();

  float qv = 0.0f;
#pragma unroll
  for (int i = 0; i < 4; ++i)
#pragma unroll
    for (int j = 0; j < 4; ++j) { float d = v[i][j] - mean; qv += d * d; }
#pragma unroll
  for (int o = 32; o > 0; o >>= 1) qv += __shfl_xor(qv, o, 64);
  if ((t & 63) == 0) sm[t >> 6] = qv;
  __syncthreads();
  const float varr = (sm[0] + sm[1] + sm[2] + sm[3]) * (1.0f / DLAT);
  const float rs = rsqrtf(varr + 1e-5f);

  bf16_t* outr = xn + (size_t)row * DLAT;
#pragma unroll
  for (int i = 0; i < 4; ++i) {
    bf16x4 o;
#pragma unroll
    for (int j = 0; j < 4; ++j) o[j] = f2bf((v[i][j] - mean) * rs);
    *(bf16x4*)(outr + (t + i * 256) * 4) = o;
  }
}

// -------- row softmax over V=32000, bf16 in-place, row staged in LDS --------
__global__ void __launch_bounds__(256)
softmax_k(bf16_t* __restrict__ L)
{
  __shared__ __align__(16) bf16_t rs_[VOCAB];
  __shared__ float sm[4];
  const int row = blockIdx.x, t = threadIdx.x;
  bf16_t* lrow = L + (size_t)row * VOCAB;
  const int NF = VOCAB / 8;

  float m = -3.0e38f;
  for (int f = t; f < NF; f += 256) {
    u16x8 u = *(const u16x8*)(&lrow[f * 8]);
    *(u16x8*)(&rs_[f * 8]) = u;
#pragma unroll
    for (int j = 0; j < 8; ++j) m = fmaxf(m, bf2f(u[j]));
  }
#pragma unroll
  for (int o = 32; o > 0; o >>= 1) m = fmaxf(m, __shfl_xor(m, o, 64));
  if ((t & 63) == 0) sm[t >> 6] = m;
  __syncthreads();
  m = fmaxf(fmaxf(sm[0], sm[1]), fmaxf(sm[2], sm[3]));
  __syncthreads();

  float s = 0.0f;
  for (int f = t; f < NF; f += 256) {
    u16x8 u = *(const u16x8*)(&rs_[f * 8]);
#pragma unroll
    for (int j = 0; j < 8; ++j) s += __expf(bf2f(u[j]) - m);
  }
#pragma unroll
  for (int o = 32; o > 0; o >>= 1) s += __shfl_xor(s, o, 64);
  if ((t & 63) == 0) sm[t >> 6] = s;
  __syncthreads();
  const float inv = 1.0f / (sm[0] + sm[1] + sm[2] + sm[3]);

  for (int f = t; f < NF; f += 256) {
    u16x8 u = *(const u16x8*)(&rs_[f * 8]);
    bf16x8 o;
#pragma unroll
    for (int j = 0; j < 8; ++j) o[j] = f2bf(__expf(bf2f(u[j]) - m) * inv);
    *(bf16x8*)(&lrow[f * 8]) = o;
  }
}

extern "C" void kernel_launch(void* const* d_in, const int* in_sizes, int n_in,
                              void* d_out, int out_size, void* d_ws, size_t ws_size,
                              hipStream_t stream)
{
  (void)in_sizes; (void)n_in; (void)out_size;
  const float* vision = (const float*)d_in[0];   // [2304][1024]
  const float* W1w    = (const float*)d_in[1];   // [4096][1024]
  const float* W1b    = (const float*)d_in[2];   // [4096]
  const float* W2w    = (const float*)d_in[3];   // [32000][4096]
  const float* Emb    = (const float*)d_in[4];   // [32000][4096]
  float* out = (float*)d_out;                    // [2304][4096]

  // layout: xn | logits | xbuf(=p1) | wslot (xnv,w1b carved inside) | p2 | p3
  char* ws = (char*)d_ws;
  bf16_t* xn     = (bf16_t*)ws;                          //  18,874,368
  bf16_t* logits = (bf16_t*)(ws + 18874368);             // 147,456,000
  float*  xbuf   = (float*)(ws + 166330368);             //  37,748,736
  bf16_t* wslot  = (bf16_t*)(ws + 204079104);            // 262,144,000
  bf16_t* xnv    = (bf16_t*)(ws + 204079104);            // inside wslot
  bf16_t* w1b    = (bf16_t*)(ws + 208797696);            // inside wslot
  float*  p2     = (float*)(ws + 466223104);
  float*  p3     = (float*)(ws + 503971840);
  const size_t NEED4 = 541720576ull;

  // 0) convert vision + W1 to bf16
  cvt_bf16_k<<<dim3(512), dim3(256), 0, stream>>>(vision, xnv, (long)M_TOK * DV / 8);
  cvt_bf16_k<<<dim3(512), dim3(256), 0, stream>>>(W1w, w1b, (long)DLAT * DV / 8);

  // 1) x = vision @ W1^T + b   (128^2, grid 576)
  gemm_bb1<<<dim3(18 * 32), dim3(256), 0, stream>>>(
      xnv, w1b, xbuf, W1b, DV, DV, DLAT, 18);

  // 2) xn = LayerNorm(x) -> bf16
  ln_k<<<dim3(M_TOK), dim3(256), 0, stream>>>(xbuf, xn);

  // 3a) W2 -> bf16
  cvt_bf16_k<<<dim3(2048), dim3(256), 0, stream>>>(W2w, wslot, (long)VOCAB * DLAT / 8);

  // 3b) logits = xn @ W2b^T -> bf16  (256x128 tiles: grid 9*250 = 2250)
  gemm256r<1><<<dim3(9 * 250), dim3(256), 0, stream>>>(
      xn, wslot, logits, nullptr, nullptr, nullptr, DLAT, DLAT, VOCAB, 9, 250);

  // 4) Emb -> EmbT bf16 [4096][32000] (reuses wslot)
  embT_k<<<dim3((VOCAB / 64) * (DLAT / 64)), dim3(256), 0, stream>>>(Emb, wslot);

  // 5) P = softmax(logits) in place
  softmax_k<<<dim3(M_TOK), dim3(256), 0, stream>>>(logits);

  // 6) out = P @ EmbT^T  (256x128 tiles, split-K=4: grid 9*32*4 = 1152)
  if (ws_size >= NEED4) {
    gemm256r<2><<<dim3(9 * 32 * 4), dim3(256), 0, stream>>>(
        logits, wslot, out, xbuf, p2, p3, VOCAB / 4, VOCAB, DLAT, 9, 32);
    addk3<<<dim3(1024), dim3(256), 0, stream>>>(out, xbuf, p2, p3, (M_TOK * DLAT) / 4);
  } else {
    gemm256r<2><<<dim3(9 * 32 * 2), dim3(256), 0, stream>>>(
        logits, wslot, out, xbuf, nullptr, nullptr, VOCAB / 2, VOCAB, DLAT, 9, 32);
    addk<<<dim3(1024), dim3(256), 0, stream>>>(out, xbuf, (M_TOK * DLAT) / 4);
  }
}

// Round 21
// 1885.300 us; speedup vs baseline: 1.0561x; 1.0561x over previous
//
#include <hip/hip_runtime.h>
#include <hip/hip_bf16.h>
#include <stdint.h>

typedef __bf16 bf16_t;
typedef __attribute__((ext_vector_type(8))) __bf16 bf16x8;
typedef __attribute__((ext_vector_type(4))) __bf16 bf16x4;
typedef __attribute__((ext_vector_type(4))) float f32x4;
typedef __attribute__((ext_vector_type(8))) unsigned short u16x8;

#define M_TOK 2304
#define DV    1024
#define DLAT  4096
#define VOCAB 32000

__device__ __forceinline__ float bf2f(unsigned short u) {
  union { unsigned int i; float f; } v; v.i = ((unsigned int)u) << 16; return v.f;
}
__device__ __forceinline__ bf16_t f2bf(float f) { return (bf16_t)f; }

// async global->LDS, 16B per lane; LDS dest = wave-uniform base + lane*16
#define GLOAD16(gp, lp) \
  __builtin_amdgcn_global_load_lds( \
      (const __attribute__((address_space(1))) unsigned int*)(const void*)(gp), \
      (__attribute__((address_space(3))) unsigned int*)(void*)(lp), 16, 0, 0)

// ========= 128x128 bf16 NT GEMM (R9-proven: 3-buf, vmcnt(4), 0-conflict) ====
// A [M][ld] bf16 rm, B [N][ld] bf16 rm. Split-K via sp when grid > Mt*Nt.
// Swizzle (PMC-verified 0 conflicts): global col pre-permute
// (l&3)^((l>>3)&3) on staging + XOR slot kc^((lr>>1)&3) on reads.
// EPI: 0 = f32 + bias, 1 = bf16, 2 = f32 split (sp -> Cp/Cp2/Cp3/Cp4).
constexpr int GBM = 128, GBN = 128, GBK = 32;

template<int EPI>
__global__ void __launch_bounds__(256, 3)
gemm_bb(const bf16_t* __restrict__ Ap, const bf16_t* __restrict__ Bp,
        void* __restrict__ Cp, void* __restrict__ Cp2,
        void* __restrict__ Cp3, void* __restrict__ Cp4,
        const float* __restrict__ bias,
        int Ksplit, int ld, int ldc, int Mt, int Nt)
{
  __shared__ __align__(16) bf16_t Al[3][GBM * GBK];  // 3 x 8 KB
  __shared__ __align__(16) bf16_t Bl[3][GBN * GBK];  // 3 x 8 KB

  // bijective XCD-chunked swizzle (m204)
  const int nwg = gridDim.x;
  const int orig = blockIdx.x;
  const int q = nwg >> 3, r = nwg & 7;
  const int xcd = orig & 7, idx = orig >> 3;
  const int wg = (xcd < r ? xcd * (q + 1) : r * (q + 1) + (xcd - r) * q) + idx;
  const int mt = wg % Mt;
  const int nt = (wg / Mt) % Nt;        // consecutive wg share B panel
  const int sp = wg / (Mt * Nt);        // split-K index (0 when unsplit)
  const int m0 = mt * GBM, n0 = nt * GBN;
  const int kbase = sp * Ksplit;

  const int t    = threadIdx.x;
  const int lane = t & 63, wv = t >> 6;
  const int wm = wv >> 1, wn = wv & 1;     // wave grid 2x2: per-wave 64x64
  const int lr = lane & 15, kc = lane >> 4;

  f32x4 acc[4][4];
#pragma unroll
  for (int i = 0; i < 4; ++i)
#pragma unroll
    for (int j = 0; j < 4; ++j)
#pragma unroll
      for (int x = 0; x < 4; ++x) acc[i][j][x] = 0.0f;

  const int rql = lane >> 2;
  const int cbs = (((lane & 3) ^ ((lane >> 3) & 3)) * 16);  // swizzled col byte
  const int sw8 = (kc ^ ((lr >> 1) & 3)) * 8;               // read-side XOR slot
  const size_t rstride = (size_t)ld * 2;

  const int NT = Ksplit / GBK;

  auto STAGE = [&](int kt, int nb) {
    const size_t kb = (size_t)(kbase + kt * GBK) * 2;
    const char* ga = (const char*)Ap + (size_t)(m0 + wv * 32 + rql) * rstride + kb + cbs;
    char* la = (char*)&Al[nb][0] + wv * 2048;
    GLOAD16(ga, la);
    GLOAD16(ga + 16 * rstride, la + 1024);
    const char* gb = (const char*)Bp + (size_t)(n0 + wv * 32 + rql) * rstride + kb + cbs;
    char* lb = (char*)&Bl[nb][0] + wv * 2048;
    GLOAD16(gb, lb);
    GLOAD16(gb + 16 * rstride, lb + 1024);
  };

  auto COMPUTE = [&](int nb) {
    bf16x8 af[4], bfv[4];
#pragma unroll
    for (int f = 0; f < 4; ++f)
      af[f] = *(const bf16x8*)(&Al[nb][(wm * 64 + f * 16 + lr) * GBK + sw8]);
#pragma unroll
    for (int f = 0; f < 4; ++f)
      bfv[f] = *(const bf16x8*)(&Bl[nb][(wn * 64 + f * 16 + lr) * GBK + sw8]);
    __builtin_amdgcn_s_setprio(1);
#pragma unroll
    for (int i = 0; i < 4; ++i)
#pragma unroll
      for (int j = 0; j < 4; ++j)
        acc[i][j] = __builtin_amdgcn_mfma_f32_16x16x32_bf16(af[i], bfv[j], acc[i][j], 0, 0, 0);
    __builtin_amdgcn_s_setprio(0);
  };

  auto BARX = [&]() {
    asm volatile("s_waitcnt lgkmcnt(0)" ::: "memory");
    __builtin_amdgcn_s_barrier();
  };

  // prologue: stage tiles 0,1; wait tile 0 only (tile 1 stays in flight)
  STAGE(0, 0);
  STAGE(1, 1);
  asm volatile("s_waitcnt vmcnt(4)" ::: "memory");
  __builtin_amdgcn_s_barrier();

  int bc = 0, bn = 1, bs = 2;
  for (int kt = 0; kt < NT - 2; ++kt) {
    STAGE(kt + 2, bs);                  // 4 loads fly under COMPUTE + barrier
    COMPUTE(bc);
    asm volatile("s_waitcnt vmcnt(4)" ::: "memory");  // tile kt+1 landed
    BARX();
    const int tmp = bc; bc = bn; bn = bs; bs = tmp;
  }
  COMPUTE(bc);
  asm volatile("s_waitcnt vmcnt(0)" ::: "memory");
  BARX();
  COMPUTE(bn);

  // epilogue
  float* Cf = nullptr;
  if (EPI == 2)
    Cf = (sp == 0) ? (float*)Cp : (sp == 1) ? (float*)Cp2
       : (sp == 2) ? (float*)Cp3 : (float*)Cp4;
  else
    Cf = (float*)Cp;
#pragma unroll
  for (int j = 0; j < 4; ++j) {
    const int col = n0 + wn * 64 + j * 16 + lr;
    float bv = 0.0f;
    if (EPI == 0) bv = bias[col];
#pragma unroll
    for (int i = 0; i < 4; ++i) {
      const int row = m0 + wm * 64 + i * 16 + kc * 4;
      f32x4 a4 = acc[i][j];
      if (EPI == 1) {
        bf16_t* C = (bf16_t*)Cp;
#pragma unroll
        for (int x = 0; x < 4; ++x) C[(size_t)(row + x) * ldc + col] = f2bf(a4[x]);
      } else if (EPI == 0) {
#pragma unroll
        for (int x = 0; x < 4; ++x) Cf[(size_t)(row + x) * ldc + col] = a4[x] + bv;
      } else {
#pragma unroll
        for (int x = 0; x < 4; ++x) Cf[(size_t)(row + x) * ldc + col] = a4[x];
      }
    }
  }
}

// -------- out += partial(s) (split-K reduction), f32 --------
__global__ void __launch_bounds__(256)
addk(float* __restrict__ out, const float* __restrict__ part, int n4)
{
  const int stride = gridDim.x * 256;
  for (int i = blockIdx.x * 256 + threadIdx.x; i < n4; i += stride) {
    f32x4 a = *(const f32x4*)(out + i * 4);
    f32x4 b = *(const f32x4*)(part + i * 4);
#pragma unroll
    for (int x = 0; x < 4; ++x) a[x] += b[x];
    *(f32x4*)(out + i * 4) = a;
  }
}

__global__ void __launch_bounds__(256)
addk3(float* __restrict__ out, const float* __restrict__ pa,
      const float* __restrict__ pb, const float* __restrict__ pc, int n4)
{
  const int stride = gridDim.x * 256;
  for (int i = blockIdx.x * 256 + threadIdx.x; i < n4; i += stride) {
    f32x4 a = *(const f32x4*)(out + i * 4);
    f32x4 b = *(const f32x4*)(pa + i * 4);
    f32x4 c = *(const f32x4*)(pb + i * 4);
    f32x4 d = *(const f32x4*)(pc + i * 4);
#pragma unroll
    for (int x = 0; x < 4; ++x) a[x] += b[x] + c[x] + d[x];
    *(f32x4*)(out + i * 4) = a;
  }
}

// -------- stream convert f32 -> bf16 (same layout) --------
__global__ void __launch_bounds__(256)
cvt_bf16_k(const float* __restrict__ in, bf16_t* __restrict__ out, long n8)
{
  const long stride = (long)gridDim.x * 256;
  for (long i = (long)blockIdx.x * 256 + threadIdx.x; i < n8; i += stride) {
    f32x4 a = *(const f32x4*)(in + i * 8);
    f32x4 b = *(const f32x4*)(in + i * 8 + 4);
    bf16x8 o;
#pragma unroll
    for (int j = 0; j < 4; ++j) { o[j] = f2bf(a[j]); o[j + 4] = f2bf(b[j]); }
    *(bf16x8*)(out + i * 8) = o;
  }
}

// -------- Emb [32000][4096] f32 -> EmbT [4096][32000] bf16 (LDS-tiled) ------
__global__ void __launch_bounds__(256)
embT_k(const float* __restrict__ E, bf16_t* __restrict__ ET)
{
  __shared__ bf16_t tl[64][72];
  const int vb = blockIdx.x % (VOCAB / 64);
  const int eb = blockIdx.x / (VOCAB / 64);
  const int v0 = vb * 64, e0 = eb * 64;
  const int t = threadIdx.x;

  const int rr = t >> 4, c4 = (t & 15) * 4;
#pragma unroll
  for (int p = 0; p < 4; ++p) {
    const float* src = E + (size_t)(v0 + rr + p * 16) * DLAT + e0 + c4;
    f32x4 a = *(const f32x4*)src;
#pragma unroll
    for (int j = 0; j < 4; ++j) tl[c4 + j][rr + p * 16] = f2bf(a[j]);
  }
  __syncthreads();

  const int el = t >> 3, v8 = (t & 7) * 8;
#pragma unroll
  for (int p = 0; p < 2; ++p) {
    bf16x8 o = *(const bf16x8*)(&tl[el + p * 32][v8]);
    *(bf16x8*)(ET + (size_t)(e0 + el + p * 32) * VOCAB + v0 + v8) = o;
  }
}

// -------- LayerNorm over last dim (4096), f32 in -> bf16 out --------
__global__ void __launch_bounds__(256)
ln_k(const float* __restrict__ x, bf16_t* __restrict__ xn)
{
  __shared__ float sm[4];
  const int row = blockIdx.x, t = threadIdx.x;
  const float* xr = x + (size_t)row * DLAT;
  f32x4 v[4];
#pragma unroll
  for (int i = 0; i < 4; ++i) v[i] = *(const f32x4*)(xr + (t + i * 256) * 4);

  float s = 0.0f;
#pragma unroll
  for (int i = 0; i < 4; ++i)
#pragma unroll
    for (int j = 0; j < 4; ++j) s += v[i][j];
#pragma unroll
  for (int o = 32; o > 0; o >>= 1) s += __shfl_xor(s, o, 64);
  if ((t & 63) == 0) sm[t >> 6] = s;
  __syncthreads();
  const float mean = (sm[0] + sm[1] + sm[2] + sm[3]) * (1.0f / DLAT);
  __syncthreads();

  float qv = 0.0f;
#pragma unroll
  for (int i = 0; i < 4; ++i)
#pragma unroll
    for (int j = 0; j < 4; ++j) { float d = v[i][j] - mean; qv += d * d; }
#pragma unroll
  for (int o = 32; o > 0; o >>= 1) qv += __shfl_xor(qv, o, 64);
  if ((t & 63) == 0) sm[t >> 6] = qv;
  __syncthreads();
  const float varr = (sm[0] + sm[1] + sm[2] + sm[3]) * (1.0f / DLAT);
  const float rs = rsqrtf(varr + 1e-5f);

  bf16_t* outr = xn + (size_t)row * DLAT;
#pragma unroll
  for (int i = 0; i < 4; ++i) {
    bf16x4 o;
#pragma unroll
    for (int j = 0; j < 4; ++j) o[j] = f2bf((v[i][j] - mean) * rs);
    *(bf16x4*)(outr + (t + i * 256) * 4) = o;
  }
}

// -------- row softmax over V=32000, bf16 in-place, row staged in LDS --------
__global__ void __launch_bounds__(256)
softmax_k(bf16_t* __restrict__ L)
{
  __shared__ __align__(16) bf16_t rs_[VOCAB];
  __shared__ float sm[4];
  const int row = blockIdx.x, t = threadIdx.x;
  bf16_t* lrow = L + (size_t)row * VOCAB;
  const int NF = VOCAB / 8;

  float m = -3.0e38f;
  for (int f = t; f < NF; f += 256) {
    u16x8 u = *(const u16x8*)(&lrow[f * 8]);
    *(u16x8*)(&rs_[f * 8]) = u;
#pragma unroll
    for (int j = 0; j < 8; ++j) m = fmaxf(m, bf2f(u[j]));
  }
#pragma unroll
  for (int o = 32; o > 0; o >>= 1) m = fmaxf(m, __shfl_xor(m, o, 64));
  if ((t & 63) == 0) sm[t >> 6] = m;
  __syncthreads();
  m = fmaxf(fmaxf(sm[0], sm[1]), fmaxf(sm[2], sm[3]));
  __syncthreads();

  float s = 0.0f;
  for (int f = t; f < NF; f += 256) {
    u16x8 u = *(const u16x8*)(&rs_[f * 8]);
#pragma unroll
    for (int j = 0; j < 8; ++j) s += __expf(bf2f(u[j]) - m);
  }
#pragma unroll
  for (int o = 32; o > 0; o >>= 1) s += __shfl_xor(s, o, 64);
  if ((t & 63) == 0) sm[t >> 6] = s;
  __syncthreads();
  const float inv = 1.0f / (sm[0] + sm[1] + sm[2] + sm[3]);

  for (int f = t; f < NF; f += 256) {
    u16x8 u = *(const u16x8*)(&rs_[f * 8]);
    bf16x8 o;
#pragma unroll
    for (int j = 0; j < 8; ++j) o[j] = f2bf(__expf(bf2f(u[j]) - m) * inv);
    *(bf16x8*)(&lrow[f * 8]) = o;
  }
}

extern "C" void kernel_launch(void* const* d_in, const int* in_sizes, int n_in,
                              void* d_out, int out_size, void* d_ws, size_t ws_size,
                              hipStream_t stream)
{
  (void)in_sizes; (void)n_in; (void)out_size;
  const float* vision = (const float*)d_in[0];   // [2304][1024]
  const float* W1w    = (const float*)d_in[1];   // [4096][1024]
  const float* W1b    = (const float*)d_in[2];   // [4096]
  const float* W2w    = (const float*)d_in[3];   // [32000][4096]
  const float* Emb    = (const float*)d_in[4];   // [32000][4096]
  float* out = (float*)d_out;                    // [2304][4096]

  // layout: xn | logits | xbuf(=p1) | wslot (xnv,w1b carved inside) | p2 | p3
  char* ws = (char*)d_ws;
  bf16_t* xn     = (bf16_t*)ws;                          //  18,874,368
  bf16_t* logits = (bf16_t*)(ws + 18874368);             // 147,456,000
  float*  xbuf   = (float*)(ws + 166330368);             //  37,748,736
  bf16_t* wslot  = (bf16_t*)(ws + 204079104);            // 262,144,000
  bf16_t* xnv    = (bf16_t*)(ws + 204079104);            // inside wslot (dead until W2 cvt)
  bf16_t* w1b    = (bf16_t*)(ws + 208797696);            // inside wslot
  float*  p2     = (float*)(ws + 466223104);
  float*  p3     = (float*)(ws + 503971840);
  const size_t NEED4 = 541720576ull;

  // 0) convert vision + W1 to bf16
  cvt_bf16_k<<<dim3(512), dim3(256), 0, stream>>>(vision, xnv, (long)M_TOK * DV / 8);
  cvt_bf16_k<<<dim3(512), dim3(256), 0, stream>>>(W1w, w1b, (long)DLAT * DV / 8);

  // 1) x = vision @ W1^T + b   (grid 576)
  gemm_bb<0><<<dim3(18 * 32), dim3(256), 0, stream>>>(
      xnv, w1b, xbuf, nullptr, nullptr, nullptr, W1b, DV, DV, DLAT, 18, 32);

  // 2) xn = LayerNorm(x) -> bf16
  ln_k<<<dim3(M_TOK), dim3(256), 0, stream>>>(xbuf, xn);

  // 3a) W2 -> bf16
  cvt_bf16_k<<<dim3(2048), dim3(256), 0, stream>>>(W2w, wslot, (long)VOCAB * DLAT / 8);

  // 3b) logits = xn @ W2b^T -> bf16   (grid 4500, queued; 1 MB B panels)
  gemm_bb<1><<<dim3(18 * 250), dim3(256), 0, stream>>>(
      xn, wslot, logits, nullptr, nullptr, nullptr, nullptr,
      DLAT, DLAT, VOCAB, 18, 250);

  // 4) Emb -> EmbT bf16 [4096][32000] (reuses wslot)
  embT_k<<<dim3((VOCAB / 64) * (DLAT / 64)), dim3(256), 0, stream>>>(Emb, wslot);

  // 5) P = softmax(logits) in place
  softmax_k<<<dim3(M_TOK), dim3(256), 0, stream>>>(logits);

  // 6) out = P @ EmbT^T — split-K=4 (R16-proven best: 1895 us total)
  if (ws_size >= NEED4) {
    gemm_bb<2><<<dim3(18 * 32 * 4), dim3(256), 0, stream>>>(
        logits, wslot, out, xbuf, p2, p3, nullptr, VOCAB / 4, VOCAB, DLAT, 18, 32);
    addk3<<<dim3(1024), dim3(256), 0, stream>>>(out, xbuf, p2, p3, (M_TOK * DLAT) / 4);
  } else {
    gemm_bb<2><<<dim3(18 * 32 * 2), dim3(256), 0, stream>>>(
        logits, wslot, out, xbuf, nullptr, nullptr, nullptr, VOCAB / 2, VOCAB, DLAT, 18, 32);
    addk<<<dim3(1024), dim3(256), 0, stream>>>(out, xbuf, (M_TOK * DLAT) / 4);
  }
}